// Round 19
// baseline (714.850 us; speedup 1.0000x reference)
//
#include <hip/hip_runtime.h>
#include <hip/hip_bf16.h>
#include <hip/hip_fp16.h>
#include <math.h>

#define EPSF 1e-5f
#define B_N 8
#define L_N 256
#define DM_N 1024
#define DI_N 2048
#define DS_N 64
#define NH_N 32
#define HD_N 64
#define DCONV_N 2176
#define DPROJ_N 4256
#define NTOK 2048
#define FFH_N 2048
#define NPAD_INPROJ 4352  // 4256 padded to multiple of 128

typedef _Float16 f16x8 __attribute__((ext_vector_type(8)));
typedef float f32x4 __attribute__((ext_vector_type(4)));

__device__ __forceinline__ float sigf(float x) { return 1.f / (1.f + __expf(-x)); }

__device__ __forceinline__ void gll16(const void* g, void* l) {
  typedef __attribute__((address_space(1))) const void gv;
  typedef __attribute__((address_space(3))) void lv;
  __builtin_amdgcn_global_load_lds((gv*)g, (lv*)l, 16, 0, 0);
}

__device__ __forceinline__ f16x8 cvt8(float4 a, float4 b) {
  f16x8 o;
  o[0] = (_Float16)a.x; o[1] = (_Float16)a.y; o[2] = (_Float16)a.z; o[3] = (_Float16)a.w;
  o[4] = (_Float16)b.x; o[5] = (_Float16)b.y; o[6] = (_Float16)b.z; o[7] = (_Float16)b.w;
  return o;
}

// ---- all-4 weight converter: one dispatch per block-iteration (region = blockIdx.y) ----
__global__ __launch_bounds__(256) void k_wconv4(
    const float* __restrict__ s0, const float* __restrict__ s1,
    const float* __restrict__ s2, const float* __restrict__ s3,
    _Float16* __restrict__ d0, _Float16* __restrict__ d1,
    _Float16* __restrict__ d2, _Float16* __restrict__ d3) {
  int region = blockIdx.y;
  const float* src;
  _Float16* dst;
  int n, ntot;
  if (region == 0) { src = s0; dst = d0; n = DPROJ_N * DM_N; ntot = NPAD_INPROJ * DM_N; }
  else if (region == 1) { src = s1; dst = d1; n = DM_N * DI_N; ntot = n; }
  else if (region == 2) { src = s2; dst = d2; n = FFH_N * DM_N; ntot = n; }
  else { src = s3; dst = d3; n = DM_N * FFH_N; ntot = n; }
  int i = (blockIdx.x * 256 + threadIdx.x) * 8;
  if (i >= ntot) return;
  f16x8 o;
  if (i < n) {
    float4 a = *(const float4*)(src + i);
    float4 b = *(const float4*)(src + i + 4);
    o = cvt8(a, b);
  } else {
#pragma unroll
    for (int j = 0; j < 8; ++j) o[j] = (_Float16)0.f;
  }
  *(f16x8*)(dst + i) = o;
}

// ---- conv1 weights: w[32][49] fp32 -> W1t[32][64] fp16, K zero-padded ----
__global__ __launch_bounds__(256) void k_w1t(
    const float* __restrict__ w1, _Float16* __restrict__ W1t) {
  int i = blockIdx.x * 256 + threadIdx.x;
  if (i >= 32 * 64) return;
  int co = i >> 6, k = i & 63;
  W1t[i] = (k < 49) ? (_Float16)w1[co * 49 + k] : (_Float16)0.f;
}

// ---- conv1 as MFMA implicit GEMM: M=pixels(131072), N=co(32), K=49->64 ----
__global__ __launch_bounds__(256) void k_conv1m(
    const float* __restrict__ img, const _Float16* __restrict__ W1t,
    const float* __restrict__ bnp, _Float16* __restrict__ X1h) {
  __shared__ float sIn[7][264];     // x-window [2*x0-3 .. +262)
  __shared__ _Float16 sA[128][72];  // im2col rows, 144B stride
  __shared__ _Float16 sB[32][72];
  int b = blockIdx.x, y = blockIdx.y, x0 = blockIdx.z * 128;
  int t = threadIdx.x;
  {  // stage B: 32 rows x 64 k = 256 chunks of 8
    int r = t >> 3, c = (t & 7) * 8;
    *(f16x8*)&sB[r][c] = *(const f16x8*)&W1t[r * 64 + c];
  }
  const float* ip = img + (size_t)b * 64 * 1024;
#pragma unroll
  for (int r = 0; r < 7; ++r) {
    int yy = 2 * y - 3 + r;
    for (int c = t; c < 262; c += 256) {
      int xx = 2 * x0 - 3 + c;
      float v = 0.f;
      if (yy >= 0 && yy < 64 && xx >= 0 && xx < 1024) v = ip[yy * 1024 + xx];
      sIn[r][c] = v;
    }
  }
  __syncthreads();
  {  // im2col: thread -> (pixel p = t>>1, k-half = t&1)
    int p = t >> 1, half = t & 1;
    _Float16 av[32];
    if (half == 0) {
#pragma unroll
      for (int k = 0; k < 32; ++k)
        av[k] = (_Float16)sIn[k / 7][2 * p + (k % 7)];
    } else {
#pragma unroll
      for (int k = 32; k < 64; ++k)
        av[k - 32] = (k < 49) ? (_Float16)sIn[k / 7][2 * p + (k % 7)] : (_Float16)0.f;
    }
    *(f16x8*)&sA[p][half * 32 + 0] = *(f16x8*)&av[0];
    *(f16x8*)&sA[p][half * 32 + 8] = *(f16x8*)&av[8];
    *(f16x8*)&sA[p][half * 32 + 16] = *(f16x8*)&av[16];
    *(f16x8*)&sA[p][half * 32 + 24] = *(f16x8*)&av[24];
  }
  __syncthreads();
  int w = t >> 6, lane = t & 63, lr = lane & 15, kh = lane >> 4;
  f32x4 acc[2][2];
#pragma unroll
  for (int i = 0; i < 2; ++i)
#pragma unroll
    for (int j = 0; j < 2; ++j) acc[i][j] = (f32x4)(0.f);
#pragma unroll
  for (int ks = 0; ks < 2; ++ks) {
    f16x8 af[2], bf[2];
#pragma unroll
    for (int i = 0; i < 2; ++i)
      af[i] = *(const f16x8*)&sA[w * 32 + i * 16 + lr][ks * 32 + kh * 8];
#pragma unroll
    for (int j = 0; j < 2; ++j)
      bf[j] = *(const f16x8*)&sB[j * 16 + lr][ks * 32 + kh * 8];
#pragma unroll
    for (int i = 0; i < 2; ++i)
#pragma unroll
      for (int j = 0; j < 2; ++j)
        acc[i][j] = __builtin_amdgcn_mfma_f32_16x16x32_f16(af[i], bf[j], acc[i][j], 0, 0, 0);
  }
#pragma unroll
  for (int j = 0; j < 2; ++j) {
    int co = j * 16 + lr;
    float g = bnp[co], be = bnp[32 + co], mm = bnp[64 + co], vv = bnp[96 + co];
    float sc = rsqrtf(vv + EPSF) * g, sh = be - mm * sc;
#pragma unroll
    for (int i = 0; i < 2; ++i) {
#pragma unroll
      for (int rr = 0; rr < 4; ++rr) {
        int pix = w * 32 + i * 16 + kh * 4 + rr;
        int x = x0 + pix;
        X1h[((size_t)(b * 32 + y) * 512 + x) * 32 + co] =
            (_Float16)fmaf(acc[i][j][rr], sc, sh);
      }
    }
  }
}

// ---- w2[co][ci][r][s] -> W2t[rs][co][ci] fp16 ----
__global__ __launch_bounds__(256) void k_w2t(
    const float* __restrict__ w2, _Float16* __restrict__ W2t) {
  int i = blockIdx.x * 256 + threadIdx.x;
  if (i >= 49 * 64 * 32) return;
  int ci = i & 31, co = (i >> 5) & 63, rs = i >> 11;
  W2t[rs * 2048 + co * 32 + ci] = (_Float16)w2[co * 1568 + ci * 49 + rs];
}

// ---- conv2 v2: MFMA implicit GEMM, 2-rs K-steps (K=64/step, 25 steps), 64x64 tile ----
__global__ __launch_bounds__(256) void k_conv2m(
    const _Float16* __restrict__ X1h, const _Float16* __restrict__ W2t,
    const float* __restrict__ bn2p, const float* __restrict__ img,
    const float* __restrict__ dsw, const float* __restrict__ dsbnp,
    _Float16* __restrict__ Tok16) {
  __shared__ _Float16 As[2][64 * 72];
  __shared__ _Float16 Bs[2][64 * 72];
  int b = blockIdx.x, ho = blockIdx.y, wo0 = blockIdx.z * 64;
  int t = threadIdx.x;
  int w = t >> 6, lane = t & 63;
  int lr = lane & 15, kh = lane >> 4;
  int wm = w >> 1, wn = w & 1;
  f32x4 acc[2][2];
#pragma unroll
  for (int i = 0; i < 2; ++i)
#pragma unroll
    for (int j = 0; j < 2; ++j) acc[i][j] = (f32x4)(0.f);

  const _Float16* xb = X1h + (size_t)b * 32 * 512 * 32;

  auto LOADA = [&](int step, int u, f16x8& ra) {
    int c = u * 256 + t;
    int row = c >> 3, s = c & 7;
    int rsl = s >> 2, ciq = s & 3;
    int rs = step * 2 + rsl;
#pragma unroll
    for (int q = 0; q < 8; ++q) ra[q] = (_Float16)0.f;
    if (rs < 49) {
      int r = rs / 7, ss = rs - 7 * r;
      int y = 2 * ho + r - 3, xx = 2 * (wo0 + row) + ss - 3;
      if (y >= 0 && y < 32 && xx >= 0 && xx < 512)
        ra = *(const f16x8*)(xb + ((size_t)(y * 512 + xx)) * 32 + ciq * 8);
    }
  };
  auto LOADB = [&](int step, int u, f16x8& rb) {
    int c = u * 256 + t;
    int co = c >> 3, s = c & 7;
    int rsl = s >> 2, ciq = s & 3;
    int rs = step * 2 + rsl;
#pragma unroll
    for (int q = 0; q < 8; ++q) rb[q] = (_Float16)0.f;
    if (rs < 49) rb = *(const f16x8*)(W2t + rs * 2048 + co * 32 + ciq * 8);
  };

  f16x8 ra[2], rb[2];
#pragma unroll
  for (int u = 0; u < 2; ++u) { LOADA(0, u, ra[u]); LOADB(0, u, rb[u]); }
#pragma unroll
  for (int u = 0; u < 2; ++u) {
    int c = u * 256 + t, row = c >> 3, s = c & 7;
    *(f16x8*)&As[0][row * 72 + s * 8] = ra[u];
    *(f16x8*)&Bs[0][row * 72 + s * 8] = rb[u];
  }
  __syncthreads();

  int cur = 0;
  for (int st = 0; st < 25; ++st) {
    f16x8 na[2], nb[2];
    if (st + 1 < 25) {
#pragma unroll
      for (int u = 0; u < 2; ++u) { LOADA(st + 1, u, na[u]); LOADB(st + 1, u, nb[u]); }
    }
    f16x8 af[2][2], bf[2][2];
#pragma unroll
    for (int i = 0; i < 2; ++i)
#pragma unroll
      for (int kk = 0; kk < 2; ++kk)
        af[i][kk] = *(const f16x8*)&As[cur][(wm * 32 + i * 16 + lr) * 72 + (kk * 4 + kh) * 8];
#pragma unroll
    for (int j = 0; j < 2; ++j)
#pragma unroll
      for (int kk = 0; kk < 2; ++kk)
        bf[j][kk] = *(const f16x8*)&Bs[cur][(wn * 32 + j * 16 + lr) * 72 + (kk * 4 + kh) * 8];
#pragma unroll
    for (int kk = 0; kk < 2; ++kk)
#pragma unroll
      for (int i = 0; i < 2; ++i)
#pragma unroll
        for (int j = 0; j < 2; ++j)
          acc[i][j] = __builtin_amdgcn_mfma_f32_16x16x32_f16(af[i][kk], bf[j][kk], acc[i][j], 0, 0, 0);
    if (st + 1 < 25) {
#pragma unroll
      for (int u = 0; u < 2; ++u) {
        int c = u * 256 + t, row = c >> 3, s = c & 7;
        *(f16x8*)&As[cur ^ 1][row * 72 + s * 8] = na[u];
        *(f16x8*)&Bs[cur ^ 1][row * 72 + s * 8] = nb[u];
      }
      __syncthreads();
      cur ^= 1;
    }
  }

#pragma unroll
  for (int j = 0; j < 2; ++j) {
    int co = wn * 32 + j * 16 + lr;
    float g = bn2p[co], be = bn2p[64 + co], mm = bn2p[128 + co], vv = bn2p[192 + co];
    float sc = rsqrtf(vv + EPSF) * g, sh = be - mm * sc;
    float dg = dsbnp[co], dbe = dsbnp[64 + co], dmm = dsbnp[128 + co], dvv = dsbnp[192 + co];
    float dsc = rsqrtf(dvv + EPSF) * dg, dsh = dbe - dmm * dsc;
    float wv = dsw[co];
#pragma unroll
    for (int i = 0; i < 2; ++i) {
#pragma unroll
      for (int rr = 0; rr < 4; ++rr) {
        int row = wm * 32 + i * 16 + kh * 4 + rr;
        int wo = wo0 + row;
        float dval = fmaf(img[((size_t)(b * 64 + 4 * ho)) * 1024 + 4 * wo] * wv, dsc, dsh);
        float v = fmaf(acc[i][j][rr], sc, sh) + dval;
        v = v > 0.f ? v : 0.f;
        Tok16[((size_t)(b * 256 + wo)) * DM_N + co * 16 + ho] = (_Float16)v;
      }
    }
  }
}

// ------ MFMA fp16 GEMM (R11 structure): BK=64, XOR-swizzled LDS, both operands via
// global_load_lds from pre-converted fp16 weights; + T1 XCD-aware block swizzle.
// MODE 0: store. 1: bn+res. 2: relu(bn(+bias)). 3: bn(+bias)+res.
template <int MODE, int BM, int BN>
__global__ __launch_bounds__(256) void k_mgemm(
    const _Float16* __restrict__ A, const _Float16* __restrict__ W,
    int M, int N, int K,
    const float* __restrict__ bias, const float* __restrict__ bnp,
    const _Float16* __restrict__ res16, _Float16* __restrict__ C16) {
  constexpr int MI = BM / 32, NJ = BN / 32;
  __shared__ _Float16 As[2][BM * 64];
  __shared__ _Float16 Bs[2][BN * 64];
  const int t = threadIdx.x;
  const int w = t >> 6, lane = t & 63;
  const int lr = lane & 15, kh = lane >> 4;
  const int wm = w >> 1, wn = w & 1;
  // T1 swizzle: requires gridDim.x*gridDim.y % 8 == 0 (grids: 544/512/256)
  const int nmb = gridDim.y;
  const int bid = blockIdx.y * gridDim.x + blockIdx.x;
  const int cpx = (gridDim.x * nmb) >> 3;
  const int swz = (bid & 7) * cpx + (bid >> 3);
  const int m0 = (swz % nmb) * BM, n0 = (swz / nmb) * BN;
  f32x4 acc[MI][NJ];
#pragma unroll
  for (int i = 0; i < MI; ++i)
#pragma unroll
    for (int j = 0; j < NJ; ++j) acc[i][j] = (f32x4)(0.f);

  const int nt = K >> 6;
  auto STAGE = [&](int bb, int kt) {
    const int k0 = kt << 6;
#pragma unroll
    for (int it = 0; it < BM / 32; ++it) {  // A: 256 chunks/it (32 rows x 8 slots)
      int c = it * 256 + t;
      int row = c >> 3, s = c & 7;
      int kg = (s ^ (row & 7)) * 8;
      gll16(A + (size_t)(m0 + row) * K + k0 + kg, &As[bb][(size_t)c * 8]);
    }
#pragma unroll
    for (int it = 0; it < BN / 32; ++it) {  // B: fp16 weight (pre-padded rows)
      int c = it * 256 + t;
      int row = c >> 3, s = c & 7;
      int kg = (s ^ (row & 7)) * 8;
      gll16(W + (size_t)(n0 + row) * K + k0 + kg, &Bs[bb][(size_t)c * 8]);
    }
  };

  STAGE(0, 0);
  __syncthreads();
  int bb = 0;
  const int sw = lr & 7;  // row&7 for all fragment rows (offsets are multiples of 8)
  for (int kt = 0; kt < nt; ++kt) {
    if (kt + 1 < nt) STAGE(bb ^ 1, kt + 1);
    f16x8 af[MI][2], bf[NJ][2];
#pragma unroll
    for (int i = 0; i < MI; ++i)
#pragma unroll
      for (int kk = 0; kk < 2; ++kk)
        af[i][kk] = *(const f16x8*)&As[bb][(size_t)(wm * (BM / 2) + i * 16 + lr) * 64 +
                                           ((kk * 4 + kh) ^ sw) * 8];
#pragma unroll
    for (int j = 0; j < NJ; ++j)
#pragma unroll
      for (int kk = 0; kk < 2; ++kk)
        bf[j][kk] = *(const f16x8*)&Bs[bb][(size_t)(wn * (BN / 2) + j * 16 + lr) * 64 +
                                           ((kk * 4 + kh) ^ sw) * 8];
#pragma unroll
    for (int kk = 0; kk < 2; ++kk)
#pragma unroll
      for (int i = 0; i < MI; ++i)
#pragma unroll
        for (int j = 0; j < NJ; ++j)
          acc[i][j] = __builtin_amdgcn_mfma_f32_16x16x32_f16(af[i][kk], bf[j][kk], acc[i][j], 0, 0, 0);
    __syncthreads();
    bb ^= 1;
  }

#pragma unroll
  for (int j = 0; j < NJ; ++j) {
    int cn = n0 + wn * (BN / 2) + j * 16 + lr;
    if (cn >= N) continue;
    float sc = 1.f, sh = 0.f, bs = 0.f;
    if (MODE >= 1) {
      float g = bnp[cn], be = bnp[N + cn];
      float mm = bnp[2 * N + cn], vv = bnp[3 * N + cn];
      sc = rsqrtf(vv + EPSF) * g;
      sh = be - mm * sc;
    }
    if (MODE == 2 || MODE == 3) bs = bias[cn];
#pragma unroll
    for (int i = 0; i < MI; ++i) {
#pragma unroll
      for (int rr = 0; rr < 4; ++rr) {
        int r = m0 + wm * (BM / 2) + i * 16 + kh * 4 + rr;
        float v = acc[i][j][rr];
        if (MODE == 2 || MODE == 3) v += bs;
        if (MODE >= 1) v = fmaf(v, sc, sh);
        if (MODE == 2) v = v > 0.f ? v : 0.f;
        size_t o = (size_t)r * N + cn;
        if (MODE == 1 || MODE == 3) v += (float)res16[o];
        C16[o] = (_Float16)v;
      }
    }
  }
}

// ------- causal depthwise conv1d + silu on xBC (fp16 in/out); softplus dt; LOG-decay -------
__global__ __launch_bounds__(256) void k_convprep(
    const _Float16* __restrict__ ZX16, const float* __restrict__ cw,
    const float* __restrict__ cb, const float* __restrict__ dtb,
    const float* __restrict__ Alog, _Float16* __restrict__ XBC16,
    float* __restrict__ DT, float* __restrict__ DLA) {
  int m = blockIdx.x;
  int c = blockIdx.y * 256 + threadIdx.x;
  int l = m & 255;
  if (c < DCONV_N) {
    const float* cwp = cw + c * 4;
    float acc = cb[c];
#pragma unroll
    for (int k = 0; k < 4; ++k) {
      int dl = l + k - 3;
      if (dl >= 0)
        acc = fmaf((float)ZX16[(size_t)(m + k - 3) * DPROJ_N + DI_N + c], cwp[k], acc);
    }
    XBC16[(size_t)m * DCONV_N + c] = (_Float16)(acc * sigf(acc));
  } else if (c < DCONV_N + NH_N) {
    int h = c - DCONV_N;
    float xx = (float)ZX16[(size_t)m * DPROJ_N + DI_N + DCONV_N + h] + dtb[h];
    float dt = xx > 20.f ? xx : log1pf(__expf(xx));
    DT[m * NH_N + h] = dt;
    DLA[m * NH_N + h] = -dt * __expf(Alog[h]);  // log(dA), always finite, <= 0
  }
}

// ------- selective scan v3: Mamba2 SSD chunked, MFMA. grid 256=(b,h), 256 thr (4 waves) -------
__global__ __launch_bounds__(256) void k_scan(
    const _Float16* __restrict__ XBC16, const float* __restrict__ DT,
    const float* __restrict__ DLA, const float* __restrict__ Dp,
    float* __restrict__ Y) {
  __shared__ _Float16 sC[64][72];    // C[l][n]
  __shared__ _Float16 sB[64][72];    // B[l][n]
  __shared__ _Float16 sBts[64][72];  // [n][j] = B[j][n]*es[j]
  __shared__ _Float16 sXt[64][72];   // [p][l] = dt[l]*x[l][p]
  __shared__ _Float16 sP[64][72];    // P[l][j]
  __shared__ _Float16 sH[64][72];    // h[p][n] fp16 mirror
  __shared__ float sH32[64][68];     // h[p][n] fp32 master
  __shared__ float sS[64], sEl[64], sEs[64], sDt[64];
  __shared__ float sCpt;

  const int b = blockIdx.x >> 5, h = blockIdx.x & 31;
  const int t = threadIdx.x;
  const int w = t >> 6, lane = t & 63;
  const int lr = lane & 15, kh = lane >> 4;
  const float Dh = Dp[h];

  {  // zero h
    _Float16* hp = &sH[0][0];
    float* h32p = &sH32[0][0];
    for (int i = t; i < 64 * 72; i += 256) hp[i] = (_Float16)0.f;
    for (int i = t; i < 64 * 68; i += 256) h32p[i] = 0.f;
  }

  for (int c = 0; c < 4; ++c) {
    const int mbase = b * L_N + c * 64;
    __syncthreads();  // A: protect LDS reuse across chunks (incl. h16 writes)

    if (t < 64) {  // B: segsum in wave 0
      int l = t;
      float v = DLA[(mbase + l) * NH_N + h];
#pragma unroll
      for (int o = 1; o < 64; o <<= 1) {
        float u = __shfl_up(v, o);
        v += (l >= o) ? u : 0.f;
      }
      sS[l] = v;
      sEl[l] = __expf(v);
      float s63 = __shfl(v, 63);
      sEs[l] = __expf(s63 - v);
      if (l == 63) sCpt = __expf(s63);
      sDt[l] = DT[(mbase + l) * NH_N + h];
    }
    __syncthreads();  // B -> C

    {  // C: build tiles. thread = (row l = t>>2, col quarter q = t&3)
      int l = t >> 2, q = t & 3;
      const _Float16* row = XBC16 + (size_t)(mbase + l) * DCONV_N;
      float dt_l = sDt[l], es_l = sEs[l];
      // B
      f16x8 b0 = *(const f16x8*)&row[DI_N + q * 16];
      f16x8 b1 = *(const f16x8*)&row[DI_N + q * 16 + 8];
      *(f16x8*)&sB[l][q * 16] = b0;
      *(f16x8*)&sB[l][q * 16 + 8] = b1;
#pragma unroll
      for (int i = 0; i < 8; ++i) {
        sBts[q * 16 + i][l] = (_Float16)((float)b0[i] * es_l);
        sBts[q * 16 + 8 + i][l] = (_Float16)((float)b1[i] * es_l);
      }
      // C
      *(f16x8*)&sC[l][q * 16] = *(const f16x8*)&row[DI_N + DS_N + q * 16];
      *(f16x8*)&sC[l][q * 16 + 8] = *(const f16x8*)&row[DI_N + DS_N + q * 16 + 8];
      // x -> Xd^T
      f16x8 x0 = *(const f16x8*)&row[h * HD_N + q * 16];
      f16x8 x1 = *(const f16x8*)&row[h * HD_N + q * 16 + 8];
#pragma unroll
      for (int i = 0; i < 8; ++i) {
        sXt[q * 16 + i][l] = (_Float16)((float)x0[i] * dt_l);
        sXt[q * 16 + 8 + i][l] = (_Float16)((float)x1[i] * dt_l);
      }
    }
    __syncthreads();  // C -> D

    // D: S = C@B^T ; Yinter = C@h^T
    f32x4 Sacc[4], Yacc[4];
#pragma unroll
    for (int j = 0; j < 4; ++j) { Sacc[j] = (f32x4)(0.f); Yacc[j] = (f32x4)(0.f); }
    {
      f16x8 aC[2];
#pragma unroll
      for (int kk = 0; kk < 2; ++kk)
        aC[kk] = *(const f16x8*)&sC[16 * w + lr][kk * 32 + kh * 8];
#pragma unroll
      for (int kk = 0; kk < 2; ++kk)
#pragma unroll
        for (int jt = 0; jt < 4; ++jt) {
          f16x8 bB = *(const f16x8*)&sB[jt * 16 + lr][kk * 32 + kh * 8];
          f16x8 bH = *(const f16x8*)&sH[jt * 16 + lr][kk * 32 + kh * 8];
          Sacc[jt] = __builtin_amdgcn_mfma_f32_16x16x32_f16(aC[kk], bB, Sacc[jt], 0, 0, 0);
          Yacc[jt] = __builtin_amdgcn_mfma_f32_16x16x32_f16(aC[kk], bH, Yacc[jt], 0, 0, 0);
        }
    }

    // E: mask P, scale Yinter rows by el
#pragma unroll
    for (int rr = 0; rr < 4; ++rr) {
      int l = 16 * w + kh * 4 + rr;
      float sl = sS[l], el = sEl[l];
#pragma unroll
      for (int jt = 0; jt < 4; ++jt) {
        int j = jt * 16 + lr;
        float pv = (j <= l) ? Sacc[jt][rr] * __expf(sl - sS[j]) : 0.f;
        sP[l][j] = (_Float16)pv;
        Yacc[jt][rr] *= el;
      }
    }
    __syncthreads();  // E -> F

    // F: Y += P@Xd^T ; Hacc = Xd^T-rows @ Bts^T
    f32x4 Hacc[4];
#pragma unroll
    for (int j = 0; j < 4; ++j) Hacc[j] = (f32x4)(0.f);
    {
      f16x8 aP[2], aX[2];
#pragma unroll
      for (int kk = 0; kk < 2; ++kk) {
        aP[kk] = *(const f16x8*)&sP[16 * w + lr][kk * 32 + kh * 8];
        aX[kk] = *(const f16x8*)&sXt[16 * w + lr][kk * 32 + kh * 8];
      }
#pragma unroll
      for (int kk = 0; kk < 2; ++kk)
#pragma unroll
        for (int jt = 0; jt < 4; ++jt) {
          f16x8 bX = *(const f16x8*)&sXt[jt * 16 + lr][kk * 32 + kh * 8];
          f16x8 bBt = *(const f16x8*)&sBts[jt * 16 + lr][kk * 32 + kh * 8];
          Yacc[jt] = __builtin_amdgcn_mfma_f32_16x16x32_f16(aP[kk], bX, Yacc[jt], 0, 0, 0);
          Hacc[jt] = __builtin_amdgcn_mfma_f32_16x16x32_f16(aX[kk], bBt, Hacc[jt], 0, 0, 0);
        }
    }

    // G: epilogue — Y out (+D skip), h update
    float cpt = sCpt;
#pragma unroll
    for (int rr = 0; rr < 4; ++rr) {
      int lrow = 16 * w + kh * 4 + rr;
      int m = mbase + lrow;
#pragma unroll
      for (int jt = 0; jt < 4; ++jt) {
        int p = jt * 16 + lr;
        float xr = (float)XBC16[(size_t)m * DCONV_N + h * HD_N + p];
        Y[(size_t)m * DI_N + h * HD_N + p] = fmaf(Dh, xr, Yacc[jt][rr]);
        float hv = fmaf(cpt, sH32[lrow][jt * 16 + lr], Hacc[jt][rr]);
        sH32[lrow][jt * 16 + lr] = hv;
        sH[lrow][jt * 16 + lr] = (_Float16)hv;
      }
    }
  }
}

// ------- gate with silu(z) + RMSNorm (over DI) -> fp16; thread owns 8 contiguous c -------
__global__ __launch_bounds__(256) void k_gatenorm(
    const float* __restrict__ Y, const _Float16* __restrict__ ZX16,
    const float* __restrict__ nw, _Float16* __restrict__ YN16) {
  int m = blockIdx.x, t = threadIdx.x;
  const float* y = Y + (size_t)m * DI_N;
  const _Float16* z = ZX16 + (size_t)m * DPROJ_N;
  int c0 = t * 8;
  float4 y0 = *(const float4*)&y[c0];
  float4 y1 = *(const float4*)&y[c0 + 4];
  f16x8 z8 = *(const f16x8*)&z[c0];
  float yv[8] = {y0.x, y0.y, y0.z, y0.w, y1.x, y1.y, y1.z, y1.w};
  float vals[8];
  float ss = 0.f;
#pragma unroll
  for (int j = 0; j < 8; ++j) {
    float zz = (float)z8[j];
    float vv = yv[j] * zz * sigf(zz);
    vals[j] = vv;
    ss = fmaf(vv, vv, ss);
  }
#pragma unroll
  for (int o = 1; o < 64; o <<= 1) ss += __shfl_xor(ss, o);
  __shared__ float sred[4];
  if ((t & 63) == 0) sred[t >> 6] = ss;
  __syncthreads();
  float tot = sred[0] + sred[1] + sred[2] + sred[3];
  float scale = rsqrtf(tot * (1.f / DI_N) + EPSF);
  float4 nw0 = *(const float4*)&nw[c0];
  float4 nw1 = *(const float4*)&nw[c0 + 4];
  float nv[8] = {nw0.x, nw0.y, nw0.z, nw0.w, nw1.x, nw1.y, nw1.z, nw1.w};
  f16x8 o;
#pragma unroll
  for (int j = 0; j < 8; ++j) o[j] = (_Float16)(vals[j] * scale * nv[j]);
  *(f16x8*)&YN16[(size_t)m * DI_N + c0] = o;
}

// ------- final transpose: Tok16[m][d] -> out[b][d][l] fp32 -------
__global__ __launch_bounds__(256) void k_transpose(
    const _Float16* __restrict__ Tok16, float* __restrict__ out) {
  __shared__ float tile[32][33];
  int d0 = blockIdx.x * 32, m0 = blockIdx.y * 32;
  int tx = threadIdx.x & 31, ty = threadIdx.x >> 5;
  for (int i = ty; i < 32; i += 8)
    tile[i][tx] = (float)Tok16[(size_t)(m0 + i) * DM_N + d0 + tx];
  __syncthreads();
  int b = m0 >> 8, l0 = m0 & 255;
  for (int i = ty; i < 32; i += 8)
    out[((size_t)b * DM_N + d0 + i) * L_N + l0 + tx] = tile[tx][i];
}

extern "C" void kernel_launch(void* const* d_in, const int* in_sizes, int n_in,
                              void* d_out, int out_size, void* d_ws, size_t ws_size,
                              hipStream_t stream) {
  const float* image = (const float*)d_in[0];
  const float* conv1_w = (const float*)d_in[1];
  const float* bn1 = (const float*)d_in[2];
  const float* conv2_w = (const float*)d_in[3];
  const float* bn2 = (const float*)d_in[4];
  const float* ds_w = (const float*)d_in[5];
  const float* ds_bn = (const float*)d_in[6];
  const float* in_proj_w = (const float*)d_in[7];
  const float* conv1d_w = (const float*)d_in[8];
  const float* conv1d_b = (const float*)d_in[9];
  const float* dt_bias = (const float*)d_in[10];
  const float* A_log = (const float*)d_in[11];
  const float* Dpar = (const float*)d_in[12];
  const float* norm_w = (const float*)d_in[13];
  const float* out_proj_w = (const float*)d_in[14];
  const float* blk_bn = (const float*)d_in[15];
  const float* ff_w1 = (const float*)d_in[16];
  const float* ff_b1 = (const float*)d_in[17];
  const float* ff_bn1 = (const float*)d_in[18];
  const float* ff_w2 = (const float*)d_in[19];
  const float* ff_b2 = (const float*)d_in[20];
  const float* ff_bn2 = (const float*)d_in[21];

  // workspace: fp32 region (YR, DT, DLA) then fp16 region (~87 MB total)
  float* ws = (float*)d_ws;
  float* YR = ws;                           // 2048*2048 fp32; stem X1h aliases this
  float* DTb = YR + (size_t)NTOK * DI_N;    // 2048*32
  float* DLAb = DTb + (size_t)NTOK * NH_N;  // 2048*32
  _Float16* Tok16 = (_Float16*)(DLAb + (size_t)NTOK * NH_N);  // 2048*1024
  _Float16* ZX16 = Tok16 + (size_t)NTOK * DM_N;               // 2048*4256
  _Float16* XBC16 = ZX16 + (size_t)NTOK * DPROJ_N;            // 2048*2176
  _Float16* YN16 = XBC16 + (size_t)NTOK * DCONV_N;            // 2048*2048
  _Float16* H116 = YN16 + (size_t)NTOK * DI_N;                // 2048*2048
  _Float16* W16a = H116 + (size_t)NTOK * DI_N;                // 4352*1024 (in_proj)
  _Float16* W16b = W16a + (size_t)NPAD_INPROJ * DM_N;         // 1024*2048 (out_proj)
  _Float16* W16c = W16b + (size_t)DM_N * DI_N;                // 2048*1024 (ff1)
  _Float16* W16d = W16c + (size_t)FFH_N * DM_N;               // 1024*2048 (ff2)
  _Float16* W2t = W16d + (size_t)DM_N * FFH_N;                // 49*64*32
  _Float16* W1t = W2t + (size_t)49 * 64 * 32;                 // 32*64
  _Float16* X1h = (_Float16*)YR;

  k_w1t<<<8, 256, 0, stream>>>(conv1_w, W1t);
  k_conv1m<<<dim3(8, 32, 4), 256, 0, stream>>>(image, W1t, bn1, X1h);
  k_w2t<<<(49 * 64 * 32 + 255) / 256, 256, 0, stream>>>(conv2_w, W2t);
  k_conv2m<<<dim3(8, 16, 4), 256, 0, stream>>>(X1h, W2t, bn2, image, ds_w, ds_bn, Tok16);

  for (int i = 0; i < 4; ++i) {
    const float* Wi = in_proj_w + (size_t)i * DPROJ_N * DM_N;
    const float* cw = conv1d_w + (size_t)i * DCONV_N * 4;
    const float* cb = conv1d_b + (size_t)i * DCONV_N;
    const float* dtb = dt_bias + i * NH_N;
    const float* al = A_log + i * NH_N;
    const float* dd = Dpar + i * NH_N;
    const float* nw = norm_w + i * DI_N;
    const float* Wo = out_proj_w + (size_t)i * DM_N * DI_N;
    const float* bbn = blk_bn + (size_t)i * 4 * DM_N;
    const float* w1 = ff_w1 + (size_t)i * FFH_N * DM_N;
    const float* b1 = ff_b1 + i * FFH_N;
    const float* fbn1 = ff_bn1 + (size_t)i * 4 * FFH_N;
    const float* w2 = ff_w2 + (size_t)i * DM_N * FFH_N;
    const float* b2 = ff_b2 + i * DM_N;
    const float* fbn2 = ff_bn2 + (size_t)i * 4 * DM_N;

    // all 4 weight conversions in ONE dispatch
    k_wconv4<<<dim3(2176, 4), 256, 0, stream>>>(Wi, Wo, w1, w2, W16a, W16b, W16c, W16d);

    // in_proj: ZX16[2048,4256] = Tok16 x Wi^T   (128x128 tile -> 544 blocks)
    k_mgemm<0, 128, 128><<<dim3(34, 16), 256, 0, stream>>>(
        Tok16, W16a, NTOK, DPROJ_N, DM_N, nullptr, nullptr, nullptr, ZX16);
    k_convprep<<<dim3(NTOK, 9), 256, 0, stream>>>(ZX16, cw, cb, dtb, al, XBC16, DTb, DLAb);
    k_scan<<<256, 256, 0, stream>>>(XBC16, DTb, DLAb, dd, YR);
    k_gatenorm<<<NTOK, 256, 0, stream>>>(YR, ZX16, nw, YN16);
    // out_proj: Tok16 = bn(YN16 x Wo^T) + Tok16   (64x64 -> 512 blocks)
    k_mgemm<1, 64, 64><<<dim3(16, 32), 256, 0, stream>>>(
        YN16, W16b, NTOK, DM_N, DI_N, nullptr, bbn, Tok16, Tok16);
    // ff1: H116 = relu(bn(Tok16 x w1^T + b1))   (128x128 -> 256 blocks)
    k_mgemm<2, 128, 128><<<dim3(16, 16), 256, 0, stream>>>(
        Tok16, W16c, NTOK, FFH_N, DM_N, b1, fbn1, nullptr, H116);
    // ff2: Tok16 = bn(H116 x w2^T + b2) + Tok16   (64x64 -> 512 blocks)
    k_mgemm<3, 64, 64><<<dim3(16, 32), 256, 0, stream>>>(
        H116, W16d, NTOK, DM_N, FFH_N, b2, fbn2, Tok16, Tok16);
  }
  k_transpose<<<dim3(32, 64), 256, 0, stream>>>(Tok16, (float*)d_out);
}

// Round 20
// 675.294 us; speedup vs baseline: 1.0586x; 1.0586x over previous
//
#include <hip/hip_runtime.h>
#include <hip/hip_bf16.h>
#include <hip/hip_fp16.h>
#include <math.h>

#define EPSF 1e-5f
#define B_N 8
#define L_N 256
#define DM_N 1024
#define DI_N 2048
#define DS_N 64
#define NH_N 32
#define HD_N 64
#define DCONV_N 2176
#define DPROJ_N 4256
#define NTOK 2048
#define FFH_N 2048
#define NPAD_INPROJ 4352  // 4256 padded to multiple of 128

typedef _Float16 f16x8 __attribute__((ext_vector_type(8)));
typedef float f32x4 __attribute__((ext_vector_type(4)));

__device__ __forceinline__ float sigf(float x) { return 1.f / (1.f + __expf(-x)); }

__device__ __forceinline__ void gll16(const void* g, void* l) {
  typedef __attribute__((address_space(1))) const void gv;
  typedef __attribute__((address_space(3))) void lv;
  __builtin_amdgcn_global_load_lds((gv*)g, (lv*)l, 16, 0, 0);
}

__device__ __forceinline__ f16x8 cvt8(float4 a, float4 b) {
  f16x8 o;
  o[0] = (_Float16)a.x; o[1] = (_Float16)a.y; o[2] = (_Float16)a.z; o[3] = (_Float16)a.w;
  o[4] = (_Float16)b.x; o[5] = (_Float16)b.y; o[6] = (_Float16)b.z; o[7] = (_Float16)b.w;
  return o;
}

// ---- all-4 weight converter: one dispatch per block-iteration (region = blockIdx.y) ----
__global__ __launch_bounds__(256) void k_wconv4(
    const float* __restrict__ s0, const float* __restrict__ s1,
    const float* __restrict__ s2, const float* __restrict__ s3,
    _Float16* __restrict__ d0, _Float16* __restrict__ d1,
    _Float16* __restrict__ d2, _Float16* __restrict__ d3) {
  int region = blockIdx.y;
  const float* src;
  _Float16* dst;
  int n, ntot;
  if (region == 0) { src = s0; dst = d0; n = DPROJ_N * DM_N; ntot = NPAD_INPROJ * DM_N; }
  else if (region == 1) { src = s1; dst = d1; n = DM_N * DI_N; ntot = n; }
  else if (region == 2) { src = s2; dst = d2; n = FFH_N * DM_N; ntot = n; }
  else { src = s3; dst = d3; n = DM_N * FFH_N; ntot = n; }
  int i = (blockIdx.x * 256 + threadIdx.x) * 8;
  if (i >= ntot) return;
  f16x8 o;
  if (i < n) {
    float4 a = *(const float4*)(src + i);
    float4 b = *(const float4*)(src + i + 4);
    o = cvt8(a, b);
  } else {
#pragma unroll
    for (int j = 0; j < 8; ++j) o[j] = (_Float16)0.f;
  }
  *(f16x8*)(dst + i) = o;
}

// ---- conv1 weights: w[32][49] fp32 -> W1t[32][64] fp16, K zero-padded ----
__global__ __launch_bounds__(256) void k_w1t(
    const float* __restrict__ w1, _Float16* __restrict__ W1t) {
  int i = blockIdx.x * 256 + threadIdx.x;
  if (i >= 32 * 64) return;
  int co = i >> 6, k = i & 63;
  W1t[i] = (k < 49) ? (_Float16)w1[co * 49 + k] : (_Float16)0.f;
}

// ---- conv1 as MFMA implicit GEMM: M=pixels(131072), N=co(32), K=49->64 ----
__global__ __launch_bounds__(256) void k_conv1m(
    const float* __restrict__ img, const _Float16* __restrict__ W1t,
    const float* __restrict__ bnp, _Float16* __restrict__ X1h) {
  __shared__ float sIn[7][264];     // x-window [2*x0-3 .. +262)
  __shared__ _Float16 sA[128][72];  // im2col rows, 144B stride
  __shared__ _Float16 sB[32][72];
  int b = blockIdx.x, y = blockIdx.y, x0 = blockIdx.z * 128;
  int t = threadIdx.x;
  {  // stage B: 32 rows x 64 k = 256 chunks of 8
    int r = t >> 3, c = (t & 7) * 8;
    *(f16x8*)&sB[r][c] = *(const f16x8*)&W1t[r * 64 + c];
  }
  const float* ip = img + (size_t)b * 64 * 1024;
#pragma unroll
  for (int r = 0; r < 7; ++r) {
    int yy = 2 * y - 3 + r;
    for (int c = t; c < 262; c += 256) {
      int xx = 2 * x0 - 3 + c;
      float v = 0.f;
      if (yy >= 0 && yy < 64 && xx >= 0 && xx < 1024) v = ip[yy * 1024 + xx];
      sIn[r][c] = v;
    }
  }
  __syncthreads();
  {  // im2col: thread -> (pixel p = t>>1, k-half = t&1)
    int p = t >> 1, half = t & 1;
    _Float16 av[32];
    if (half == 0) {
#pragma unroll
      for (int k = 0; k < 32; ++k)
        av[k] = (_Float16)sIn[k / 7][2 * p + (k % 7)];
    } else {
#pragma unroll
      for (int k = 32; k < 64; ++k)
        av[k - 32] = (k < 49) ? (_Float16)sIn[k / 7][2 * p + (k % 7)] : (_Float16)0.f;
    }
    *(f16x8*)&sA[p][half * 32 + 0] = *(f16x8*)&av[0];
    *(f16x8*)&sA[p][half * 32 + 8] = *(f16x8*)&av[8];
    *(f16x8*)&sA[p][half * 32 + 16] = *(f16x8*)&av[16];
    *(f16x8*)&sA[p][half * 32 + 24] = *(f16x8*)&av[24];
  }
  __syncthreads();
  int w = t >> 6, lane = t & 63, lr = lane & 15, kh = lane >> 4;
  f32x4 acc[2][2];
#pragma unroll
  for (int i = 0; i < 2; ++i)
#pragma unroll
    for (int j = 0; j < 2; ++j) acc[i][j] = (f32x4)(0.f);
#pragma unroll
  for (int ks = 0; ks < 2; ++ks) {
    f16x8 af[2], bf[2];
#pragma unroll
    for (int i = 0; i < 2; ++i)
      af[i] = *(const f16x8*)&sA[w * 32 + i * 16 + lr][ks * 32 + kh * 8];
#pragma unroll
    for (int j = 0; j < 2; ++j)
      bf[j] = *(const f16x8*)&sB[j * 16 + lr][ks * 32 + kh * 8];
#pragma unroll
    for (int i = 0; i < 2; ++i)
#pragma unroll
      for (int j = 0; j < 2; ++j)
        acc[i][j] = __builtin_amdgcn_mfma_f32_16x16x32_f16(af[i], bf[j], acc[i][j], 0, 0, 0);
  }
#pragma unroll
  for (int j = 0; j < 2; ++j) {
    int co = j * 16 + lr;
    float g = bnp[co], be = bnp[32 + co], mm = bnp[64 + co], vv = bnp[96 + co];
    float sc = rsqrtf(vv + EPSF) * g, sh = be - mm * sc;
#pragma unroll
    for (int i = 0; i < 2; ++i) {
#pragma unroll
      for (int rr = 0; rr < 4; ++rr) {
        int pix = w * 32 + i * 16 + kh * 4 + rr;
        int x = x0 + pix;
        X1h[((size_t)(b * 32 + y) * 512 + x) * 32 + co] =
            (_Float16)fmaf(acc[i][j][rr], sc, sh);
      }
    }
  }
}

// ---- w2[co][ci][r][s] -> W2t[rs][co][ci] fp16 ----
__global__ __launch_bounds__(256) void k_w2t(
    const float* __restrict__ w2, _Float16* __restrict__ W2t) {
  int i = blockIdx.x * 256 + threadIdx.x;
  if (i >= 49 * 64 * 32) return;
  int ci = i & 31, co = (i >> 5) & 63, rs = i >> 11;
  W2t[rs * 2048 + co * 32 + ci] = (_Float16)w2[co * 1568 + ci * 49 + rs];
}

// ---- conv2 v2: MFMA implicit GEMM, 2-rs K-steps (K=64/step, 25 steps), 64x64 tile ----
__global__ __launch_bounds__(256) void k_conv2m(
    const _Float16* __restrict__ X1h, const _Float16* __restrict__ W2t,
    const float* __restrict__ bn2p, const float* __restrict__ img,
    const float* __restrict__ dsw, const float* __restrict__ dsbnp,
    _Float16* __restrict__ Tok16) {
  __shared__ _Float16 As[2][64 * 72];
  __shared__ _Float16 Bs[2][64 * 72];
  int b = blockIdx.x, ho = blockIdx.y, wo0 = blockIdx.z * 64;
  int t = threadIdx.x;
  int w = t >> 6, lane = t & 63;
  int lr = lane & 15, kh = lane >> 4;
  int wm = w >> 1, wn = w & 1;
  f32x4 acc[2][2];
#pragma unroll
  for (int i = 0; i < 2; ++i)
#pragma unroll
    for (int j = 0; j < 2; ++j) acc[i][j] = (f32x4)(0.f);

  const _Float16* xb = X1h + (size_t)b * 32 * 512 * 32;

  auto LOADA = [&](int step, int u, f16x8& ra) {
    int c = u * 256 + t;
    int row = c >> 3, s = c & 7;
    int rsl = s >> 2, ciq = s & 3;
    int rs = step * 2 + rsl;
#pragma unroll
    for (int q = 0; q < 8; ++q) ra[q] = (_Float16)0.f;
    if (rs < 49) {
      int r = rs / 7, ss = rs - 7 * r;
      int y = 2 * ho + r - 3, xx = 2 * (wo0 + row) + ss - 3;
      if (y >= 0 && y < 32 && xx >= 0 && xx < 512)
        ra = *(const f16x8*)(xb + ((size_t)(y * 512 + xx)) * 32 + ciq * 8);
    }
  };
  auto LOADB = [&](int step, int u, f16x8& rb) {
    int c = u * 256 + t;
    int co = c >> 3, s = c & 7;
    int rsl = s >> 2, ciq = s & 3;
    int rs = step * 2 + rsl;
#pragma unroll
    for (int q = 0; q < 8; ++q) rb[q] = (_Float16)0.f;
    if (rs < 49) rb = *(const f16x8*)(W2t + rs * 2048 + co * 32 + ciq * 8);
  };

  f16x8 ra[2], rb[2];
#pragma unroll
  for (int u = 0; u < 2; ++u) { LOADA(0, u, ra[u]); LOADB(0, u, rb[u]); }
#pragma unroll
  for (int u = 0; u < 2; ++u) {
    int c = u * 256 + t, row = c >> 3, s = c & 7;
    *(f16x8*)&As[0][row * 72 + s * 8] = ra[u];
    *(f16x8*)&Bs[0][row * 72 + s * 8] = rb[u];
  }
  __syncthreads();

  int cur = 0;
  for (int st = 0; st < 25; ++st) {
    f16x8 na[2], nb[2];
    if (st + 1 < 25) {
#pragma unroll
      for (int u = 0; u < 2; ++u) { LOADA(st + 1, u, na[u]); LOADB(st + 1, u, nb[u]); }
    }
    f16x8 af[2][2], bf[2][2];
#pragma unroll
    for (int i = 0; i < 2; ++i)
#pragma unroll
      for (int kk = 0; kk < 2; ++kk)
        af[i][kk] = *(const f16x8*)&As[cur][(wm * 32 + i * 16 + lr) * 72 + (kk * 4 + kh) * 8];
#pragma unroll
    for (int j = 0; j < 2; ++j)
#pragma unroll
      for (int kk = 0; kk < 2; ++kk)
        bf[j][kk] = *(const f16x8*)&Bs[cur][(wn * 32 + j * 16 + lr) * 72 + (kk * 4 + kh) * 8];
#pragma unroll
    for (int kk = 0; kk < 2; ++kk)
#pragma unroll
      for (int i = 0; i < 2; ++i)
#pragma unroll
        for (int j = 0; j < 2; ++j)
          acc[i][j] = __builtin_amdgcn_mfma_f32_16x16x32_f16(af[i][kk], bf[j][kk], acc[i][j], 0, 0, 0);
    if (st + 1 < 25) {
#pragma unroll
      for (int u = 0; u < 2; ++u) {
        int c = u * 256 + t, row = c >> 3, s = c & 7;
        *(f16x8*)&As[cur ^ 1][row * 72 + s * 8] = na[u];
        *(f16x8*)&Bs[cur ^ 1][row * 72 + s * 8] = nb[u];
      }
      __syncthreads();
      cur ^= 1;
    }
  }

#pragma unroll
  for (int j = 0; j < 2; ++j) {
    int co = wn * 32 + j * 16 + lr;
    float g = bn2p[co], be = bn2p[64 + co], mm = bn2p[128 + co], vv = bn2p[192 + co];
    float sc = rsqrtf(vv + EPSF) * g, sh = be - mm * sc;
    float dg = dsbnp[co], dbe = dsbnp[64 + co], dmm = dsbnp[128 + co], dvv = dsbnp[192 + co];
    float dsc = rsqrtf(dvv + EPSF) * dg, dsh = dbe - dmm * dsc;
    float wv = dsw[co];
#pragma unroll
    for (int i = 0; i < 2; ++i) {
#pragma unroll
      for (int rr = 0; rr < 4; ++rr) {
        int row = wm * 32 + i * 16 + kh * 4 + rr;
        int wo = wo0 + row;
        float dval = fmaf(img[((size_t)(b * 64 + 4 * ho)) * 1024 + 4 * wo] * wv, dsc, dsh);
        float v = fmaf(acc[i][j][rr], sc, sh) + dval;
        v = v > 0.f ? v : 0.f;
        Tok16[((size_t)(b * 256 + wo)) * DM_N + co * 16 + ho] = (_Float16)v;
      }
    }
  }
}

// ------ MFMA fp16 GEMM (R11 structure): BK=64, XOR-swizzled LDS, both operands via
// global_load_lds from pre-converted fp16 weights; + T1 XCD-aware block swizzle.
// MODE 0: store. 1: bn+res. 2: relu(bn(+bias)). 3: bn(+bias)+res.
template <int MODE, int BM, int BN>
__global__ __launch_bounds__(256) void k_mgemm(
    const _Float16* __restrict__ A, const _Float16* __restrict__ W,
    int M, int N, int K,
    const float* __restrict__ bias, const float* __restrict__ bnp,
    const _Float16* __restrict__ res16, _Float16* __restrict__ C16) {
  constexpr int MI = BM / 32, NJ = BN / 32;
  __shared__ _Float16 As[2][BM * 64];
  __shared__ _Float16 Bs[2][BN * 64];
  const int t = threadIdx.x;
  const int w = t >> 6, lane = t & 63;
  const int lr = lane & 15, kh = lane >> 4;
  const int wm = w >> 1, wn = w & 1;
  // T1 swizzle: requires gridDim.x*gridDim.y % 8 == 0 (grids: 1088/512)
  const int nmb = gridDim.y;
  const int bid = blockIdx.y * gridDim.x + blockIdx.x;
  const int cpx = (gridDim.x * nmb) >> 3;
  const int swz = (bid & 7) * cpx + (bid >> 3);
  const int m0 = (swz % nmb) * BM, n0 = (swz / nmb) * BN;
  f32x4 acc[MI][NJ];
#pragma unroll
  for (int i = 0; i < MI; ++i)
#pragma unroll
    for (int j = 0; j < NJ; ++j) acc[i][j] = (f32x4)(0.f);

  const int nt = K >> 6;
  auto STAGE = [&](int bb, int kt) {
    const int k0 = kt << 6;
#pragma unroll
    for (int it = 0; it < BM / 32; ++it) {  // A: 256 chunks/it (32 rows x 8 slots)
      int c = it * 256 + t;
      int row = c >> 3, s = c & 7;
      int kg = (s ^ (row & 7)) * 8;
      gll16(A + (size_t)(m0 + row) * K + k0 + kg, &As[bb][(size_t)c * 8]);
    }
#pragma unroll
    for (int it = 0; it < BN / 32; ++it) {  // B: fp16 weight (pre-padded rows)
      int c = it * 256 + t;
      int row = c >> 3, s = c & 7;
      int kg = (s ^ (row & 7)) * 8;
      gll16(W + (size_t)(n0 + row) * K + k0 + kg, &Bs[bb][(size_t)c * 8]);
    }
  };

  STAGE(0, 0);
  __syncthreads();
  int bb = 0;
  const int sw = lr & 7;  // row&7 for all fragment rows (offsets are multiples of 8)
  for (int kt = 0; kt < nt; ++kt) {
    if (kt + 1 < nt) STAGE(bb ^ 1, kt + 1);
    f16x8 af[MI][2], bf[NJ][2];
#pragma unroll
    for (int i = 0; i < MI; ++i)
#pragma unroll
      for (int kk = 0; kk < 2; ++kk)
        af[i][kk] = *(const f16x8*)&As[bb][(size_t)(wm * (BM / 2) + i * 16 + lr) * 64 +
                                           ((kk * 4 + kh) ^ sw) * 8];
#pragma unroll
    for (int j = 0; j < NJ; ++j)
#pragma unroll
      for (int kk = 0; kk < 2; ++kk)
        bf[j][kk] = *(const f16x8*)&Bs[bb][(size_t)(wn * (BN / 2) + j * 16 + lr) * 64 +
                                           ((kk * 4 + kh) ^ sw) * 8];
#pragma unroll
    for (int kk = 0; kk < 2; ++kk)
#pragma unroll
      for (int i = 0; i < MI; ++i)
#pragma unroll
        for (int j = 0; j < NJ; ++j)
          acc[i][j] = __builtin_amdgcn_mfma_f32_16x16x32_f16(af[i][kk], bf[j][kk], acc[i][j], 0, 0, 0);
    __syncthreads();
    bb ^= 1;
  }

#pragma unroll
  for (int j = 0; j < NJ; ++j) {
    int cn = n0 + wn * (BN / 2) + j * 16 + lr;
    if (cn >= N) continue;
    float sc = 1.f, sh = 0.f, bs = 0.f;
    if (MODE >= 1) {
      float g = bnp[cn], be = bnp[N + cn];
      float mm = bnp[2 * N + cn], vv = bnp[3 * N + cn];
      sc = rsqrtf(vv + EPSF) * g;
      sh = be - mm * sc;
    }
    if (MODE == 2 || MODE == 3) bs = bias[cn];
#pragma unroll
    for (int i = 0; i < MI; ++i) {
#pragma unroll
      for (int rr = 0; rr < 4; ++rr) {
        int r = m0 + wm * (BM / 2) + i * 16 + kh * 4 + rr;
        float v = acc[i][j][rr];
        if (MODE == 2 || MODE == 3) v += bs;
        if (MODE >= 1) v = fmaf(v, sc, sh);
        if (MODE == 2) v = v > 0.f ? v : 0.f;
        size_t o = (size_t)r * N + cn;
        if (MODE == 1 || MODE == 3) v += (float)res16[o];
        C16[o] = (_Float16)v;
      }
    }
  }
}

// ------- causal depthwise conv1d + silu on xBC (fp16 in/out); softplus dt; LOG-decay -------
__global__ __launch_bounds__(256) void k_convprep(
    const _Float16* __restrict__ ZX16, const float* __restrict__ cw,
    const float* __restrict__ cb, const float* __restrict__ dtb,
    const float* __restrict__ Alog, _Float16* __restrict__ XBC16,
    float* __restrict__ DT, float* __restrict__ DLA) {
  int m = blockIdx.x;
  int c = blockIdx.y * 256 + threadIdx.x;
  int l = m & 255;
  if (c < DCONV_N) {
    const float* cwp = cw + c * 4;
    float acc = cb[c];
#pragma unroll
    for (int k = 0; k < 4; ++k) {
      int dl = l + k - 3;
      if (dl >= 0)
        acc = fmaf((float)ZX16[(size_t)(m + k - 3) * DPROJ_N + DI_N + c], cwp[k], acc);
    }
    XBC16[(size_t)m * DCONV_N + c] = (_Float16)(acc * sigf(acc));
  } else if (c < DCONV_N + NH_N) {
    int h = c - DCONV_N;
    float xx = (float)ZX16[(size_t)m * DPROJ_N + DI_N + DCONV_N + h] + dtb[h];
    float dt = xx > 20.f ? xx : log1pf(__expf(xx));
    DT[m * NH_N + h] = dt;
    DLA[m * NH_N + h] = -dt * __expf(Alog[h]);  // log(dA), always finite, <= 0
  }
}

// ------- selective scan v3: Mamba2 SSD chunked, MFMA. grid 256=(b,h), 256 thr (4 waves) -------
__global__ __launch_bounds__(256) void k_scan(
    const _Float16* __restrict__ XBC16, const float* __restrict__ DT,
    const float* __restrict__ DLA, const float* __restrict__ Dp,
    float* __restrict__ Y) {
  __shared__ _Float16 sC[64][72];    // C[l][n]
  __shared__ _Float16 sB[64][72];    // B[l][n]
  __shared__ _Float16 sBts[64][72];  // [n][j] = B[j][n]*es[j]
  __shared__ _Float16 sXt[64][72];   // [p][l] = dt[l]*x[l][p]
  __shared__ _Float16 sP[64][72];    // P[l][j]
  __shared__ _Float16 sH[64][72];    // h[p][n] fp16 mirror
  __shared__ float sH32[64][68];     // h[p][n] fp32 master
  __shared__ float sS[64], sEl[64], sEs[64], sDt[64];
  __shared__ float sCpt;

  const int b = blockIdx.x >> 5, h = blockIdx.x & 31;
  const int t = threadIdx.x;
  const int w = t >> 6, lane = t & 63;
  const int lr = lane & 15, kh = lane >> 4;
  const float Dh = Dp[h];

  {  // zero h
    _Float16* hp = &sH[0][0];
    float* h32p = &sH32[0][0];
    for (int i = t; i < 64 * 72; i += 256) hp[i] = (_Float16)0.f;
    for (int i = t; i < 64 * 68; i += 256) h32p[i] = 0.f;
  }

  for (int c = 0; c < 4; ++c) {
    const int mbase = b * L_N + c * 64;
    __syncthreads();  // A: protect LDS reuse across chunks (incl. h16 writes)

    if (t < 64) {  // B: segsum in wave 0
      int l = t;
      float v = DLA[(mbase + l) * NH_N + h];
#pragma unroll
      for (int o = 1; o < 64; o <<= 1) {
        float u = __shfl_up(v, o);
        v += (l >= o) ? u : 0.f;
      }
      sS[l] = v;
      sEl[l] = __expf(v);
      float s63 = __shfl(v, 63);
      sEs[l] = __expf(s63 - v);
      if (l == 63) sCpt = __expf(s63);
      sDt[l] = DT[(mbase + l) * NH_N + h];
    }
    __syncthreads();  // B -> C

    {  // C: build tiles. thread = (row l = t>>2, col quarter q = t&3)
      int l = t >> 2, q = t & 3;
      const _Float16* row = XBC16 + (size_t)(mbase + l) * DCONV_N;
      float dt_l = sDt[l], es_l = sEs[l];
      // B
      f16x8 b0 = *(const f16x8*)&row[DI_N + q * 16];
      f16x8 b1 = *(const f16x8*)&row[DI_N + q * 16 + 8];
      *(f16x8*)&sB[l][q * 16] = b0;
      *(f16x8*)&sB[l][q * 16 + 8] = b1;
#pragma unroll
      for (int i = 0; i < 8; ++i) {
        sBts[q * 16 + i][l] = (_Float16)((float)b0[i] * es_l);
        sBts[q * 16 + 8 + i][l] = (_Float16)((float)b1[i] * es_l);
      }
      // C
      *(f16x8*)&sC[l][q * 16] = *(const f16x8*)&row[DI_N + DS_N + q * 16];
      *(f16x8*)&sC[l][q * 16 + 8] = *(const f16x8*)&row[DI_N + DS_N + q * 16 + 8];
      // x -> Xd^T
      f16x8 x0 = *(const f16x8*)&row[h * HD_N + q * 16];
      f16x8 x1 = *(const f16x8*)&row[h * HD_N + q * 16 + 8];
#pragma unroll
      for (int i = 0; i < 8; ++i) {
        sXt[q * 16 + i][l] = (_Float16)((float)x0[i] * dt_l);
        sXt[q * 16 + 8 + i][l] = (_Float16)((float)x1[i] * dt_l);
      }
    }
    __syncthreads();  // C -> D

    // D: S = C@B^T ; Yinter = C@h^T
    f32x4 Sacc[4], Yacc[4];
#pragma unroll
    for (int j = 0; j < 4; ++j) { Sacc[j] = (f32x4)(0.f); Yacc[j] = (f32x4)(0.f); }
    {
      f16x8 aC[2];
#pragma unroll
      for (int kk = 0; kk < 2; ++kk)
        aC[kk] = *(const f16x8*)&sC[16 * w + lr][kk * 32 + kh * 8];
#pragma unroll
      for (int kk = 0; kk < 2; ++kk)
#pragma unroll
        for (int jt = 0; jt < 4; ++jt) {
          f16x8 bB = *(const f16x8*)&sB[jt * 16 + lr][kk * 32 + kh * 8];
          f16x8 bH = *(const f16x8*)&sH[jt * 16 + lr][kk * 32 + kh * 8];
          Sacc[jt] = __builtin_amdgcn_mfma_f32_16x16x32_f16(aC[kk], bB, Sacc[jt], 0, 0, 0);
          Yacc[jt] = __builtin_amdgcn_mfma_f32_16x16x32_f16(aC[kk], bH, Yacc[jt], 0, 0, 0);
        }
    }

    // E: mask P, scale Yinter rows by el
#pragma unroll
    for (int rr = 0; rr < 4; ++rr) {
      int l = 16 * w + kh * 4 + rr;
      float sl = sS[l], el = sEl[l];
#pragma unroll
      for (int jt = 0; jt < 4; ++jt) {
        int j = jt * 16 + lr;
        float pv = (j <= l) ? Sacc[jt][rr] * __expf(sl - sS[j]) : 0.f;
        sP[l][j] = (_Float16)pv;
        Yacc[jt][rr] *= el;
      }
    }
    __syncthreads();  // E -> F

    // F: Y += P@Xd^T ; Hacc = Xd^T-rows @ Bts^T
    f32x4 Hacc[4];
#pragma unroll
    for (int j = 0; j < 4; ++j) Hacc[j] = (f32x4)(0.f);
    {
      f16x8 aP[2], aX[2];
#pragma unroll
      for (int kk = 0; kk < 2; ++kk) {
        aP[kk] = *(const f16x8*)&sP[16 * w + lr][kk * 32 + kh * 8];
        aX[kk] = *(const f16x8*)&sXt[16 * w + lr][kk * 32 + kh * 8];
      }
#pragma unroll
      for (int kk = 0; kk < 2; ++kk)
#pragma unroll
        for (int jt = 0; jt < 4; ++jt) {
          f16x8 bX = *(const f16x8*)&sXt[jt * 16 + lr][kk * 32 + kh * 8];
          f16x8 bBt = *(const f16x8*)&sBts[jt * 16 + lr][kk * 32 + kh * 8];
          Yacc[jt] = __builtin_amdgcn_mfma_f32_16x16x32_f16(aP[kk], bX, Yacc[jt], 0, 0, 0);
          Hacc[jt] = __builtin_amdgcn_mfma_f32_16x16x32_f16(aX[kk], bBt, Hacc[jt], 0, 0, 0);
        }
    }

    // G: epilogue — Y out (+D skip), h update
    float cpt = sCpt;
#pragma unroll
    for (int rr = 0; rr < 4; ++rr) {
      int lrow = 16 * w + kh * 4 + rr;
      int m = mbase + lrow;
#pragma unroll
      for (int jt = 0; jt < 4; ++jt) {
        int p = jt * 16 + lr;
        float xr = (float)XBC16[(size_t)m * DCONV_N + h * HD_N + p];
        Y[(size_t)m * DI_N + h * HD_N + p] = fmaf(Dh, xr, Yacc[jt][rr]);
        float hv = fmaf(cpt, sH32[lrow][jt * 16 + lr], Hacc[jt][rr]);
        sH32[lrow][jt * 16 + lr] = hv;
        sH[lrow][jt * 16 + lr] = (_Float16)hv;
      }
    }
  }
}

// ------- gate with silu(z) + RMSNorm (over DI) -> fp16; thread owns 8 contiguous c -------
__global__ __launch_bounds__(256) void k_gatenorm(
    const float* __restrict__ Y, const _Float16* __restrict__ ZX16,
    const float* __restrict__ nw, _Float16* __restrict__ YN16) {
  int m = blockIdx.x, t = threadIdx.x;
  const float* y = Y + (size_t)m * DI_N;
  const _Float16* z = ZX16 + (size_t)m * DPROJ_N;
  int c0 = t * 8;
  float4 y0 = *(const float4*)&y[c0];
  float4 y1 = *(const float4*)&y[c0 + 4];
  f16x8 z8 = *(const f16x8*)&z[c0];
  float yv[8] = {y0.x, y0.y, y0.z, y0.w, y1.x, y1.y, y1.z, y1.w};
  float vals[8];
  float ss = 0.f;
#pragma unroll
  for (int j = 0; j < 8; ++j) {
    float zz = (float)z8[j];
    float vv = yv[j] * zz * sigf(zz);
    vals[j] = vv;
    ss = fmaf(vv, vv, ss);
  }
#pragma unroll
  for (int o = 1; o < 64; o <<= 1) ss += __shfl_xor(ss, o);
  __shared__ float sred[4];
  if ((t & 63) == 0) sred[t >> 6] = ss;
  __syncthreads();
  float tot = sred[0] + sred[1] + sred[2] + sred[3];
  float scale = rsqrtf(tot * (1.f / DI_N) + EPSF);
  float4 nw0 = *(const float4*)&nw[c0];
  float4 nw1 = *(const float4*)&nw[c0 + 4];
  float nv[8] = {nw0.x, nw0.y, nw0.z, nw0.w, nw1.x, nw1.y, nw1.z, nw1.w};
  f16x8 o;
#pragma unroll
  for (int j = 0; j < 8; ++j) o[j] = (_Float16)(vals[j] * scale * nv[j]);
  *(f16x8*)&YN16[(size_t)m * DI_N + c0] = o;
}

// ------- final transpose: Tok16[m][d] -> out[b][d][l] fp32 -------
__global__ __launch_bounds__(256) void k_transpose(
    const _Float16* __restrict__ Tok16, float* __restrict__ out) {
  __shared__ float tile[32][33];
  int d0 = blockIdx.x * 32, m0 = blockIdx.y * 32;
  int tx = threadIdx.x & 31, ty = threadIdx.x >> 5;
  for (int i = ty; i < 32; i += 8)
    tile[i][tx] = (float)Tok16[(size_t)(m0 + i) * DM_N + d0 + tx];
  __syncthreads();
  int b = m0 >> 8, l0 = m0 & 255;
  for (int i = ty; i < 32; i += 8)
    out[((size_t)b * DM_N + d0 + i) * L_N + l0 + tx] = tile[tx][i];
}

extern "C" void kernel_launch(void* const* d_in, const int* in_sizes, int n_in,
                              void* d_out, int out_size, void* d_ws, size_t ws_size,
                              hipStream_t stream) {
  const float* image = (const float*)d_in[0];
  const float* conv1_w = (const float*)d_in[1];
  const float* bn1 = (const float*)d_in[2];
  const float* conv2_w = (const float*)d_in[3];
  const float* bn2 = (const float*)d_in[4];
  const float* ds_w = (const float*)d_in[5];
  const float* ds_bn = (const float*)d_in[6];
  const float* in_proj_w = (const float*)d_in[7];
  const float* conv1d_w = (const float*)d_in[8];
  const float* conv1d_b = (const float*)d_in[9];
  const float* dt_bias = (const float*)d_in[10];
  const float* A_log = (const float*)d_in[11];
  const float* Dpar = (const float*)d_in[12];
  const float* norm_w = (const float*)d_in[13];
  const float* out_proj_w = (const float*)d_in[14];
  const float* blk_bn = (const float*)d_in[15];
  const float* ff_w1 = (const float*)d_in[16];
  const float* ff_b1 = (const float*)d_in[17];
  const float* ff_bn1 = (const float*)d_in[18];
  const float* ff_w2 = (const float*)d_in[19];
  const float* ff_b2 = (const float*)d_in[20];
  const float* ff_bn2 = (const float*)d_in[21];

  // workspace: fp32 region (YR, DT, DLA) then fp16 region (~87 MB total)
  float* ws = (float*)d_ws;
  float* YR = ws;                           // 2048*2048 fp32; stem X1h aliases this
  float* DTb = YR + (size_t)NTOK * DI_N;    // 2048*32
  float* DLAb = DTb + (size_t)NTOK * NH_N;  // 2048*32
  _Float16* Tok16 = (_Float16*)(DLAb + (size_t)NTOK * NH_N);  // 2048*1024
  _Float16* ZX16 = Tok16 + (size_t)NTOK * DM_N;               // 2048*4256
  _Float16* XBC16 = ZX16 + (size_t)NTOK * DPROJ_N;            // 2048*2176
  _Float16* YN16 = XBC16 + (size_t)NTOK * DCONV_N;            // 2048*2048
  _Float16* H116 = YN16 + (size_t)NTOK * DI_N;                // 2048*2048
  _Float16* W16a = H116 + (size_t)NTOK * DI_N;                // 4352*1024 (in_proj)
  _Float16* W16b = W16a + (size_t)NPAD_INPROJ * DM_N;         // 1024*2048 (out_proj)
  _Float16* W16c = W16b + (size_t)DM_N * DI_N;                // 2048*1024 (ff1)
  _Float16* W16d = W16c + (size_t)FFH_N * DM_N;               // 1024*2048 (ff2)
  _Float16* W2t = W16d + (size_t)DM_N * FFH_N;                // 49*64*32
  _Float16* W1t = W2t + (size_t)49 * 64 * 32;                 // 32*64
  _Float16* X1h = (_Float16*)YR;

  k_w1t<<<8, 256, 0, stream>>>(conv1_w, W1t);
  k_conv1m<<<dim3(8, 32, 4), 256, 0, stream>>>(image, W1t, bn1, X1h);
  k_w2t<<<(49 * 64 * 32 + 255) / 256, 256, 0, stream>>>(conv2_w, W2t);
  k_conv2m<<<dim3(8, 16, 4), 256, 0, stream>>>(X1h, W2t, bn2, image, ds_w, ds_bn, Tok16);

  for (int i = 0; i < 4; ++i) {
    const float* Wi = in_proj_w + (size_t)i * DPROJ_N * DM_N;
    const float* cw = conv1d_w + (size_t)i * DCONV_N * 4;
    const float* cb = conv1d_b + (size_t)i * DCONV_N;
    const float* dtb = dt_bias + i * NH_N;
    const float* al = A_log + i * NH_N;
    const float* dd = Dpar + i * NH_N;
    const float* nw = norm_w + i * DI_N;
    const float* Wo = out_proj_w + (size_t)i * DM_N * DI_N;
    const float* bbn = blk_bn + (size_t)i * 4 * DM_N;
    const float* w1 = ff_w1 + (size_t)i * FFH_N * DM_N;
    const float* b1 = ff_b1 + i * FFH_N;
    const float* fbn1 = ff_bn1 + (size_t)i * 4 * FFH_N;
    const float* w2 = ff_w2 + (size_t)i * DM_N * FFH_N;
    const float* b2 = ff_b2 + i * DM_N;
    const float* fbn2 = ff_bn2 + (size_t)i * 4 * DM_N;

    // all 4 weight conversions in ONE dispatch
    k_wconv4<<<dim3(2176, 4), 256, 0, stream>>>(Wi, Wo, w1, w2, W16a, W16b, W16c, W16d);

    // in_proj: ZX16[2048,4256] = Tok16 x Wi^T   (64x128 tile -> 1088 blocks)
    k_mgemm<0, 64, 128><<<dim3(34, 32), 256, 0, stream>>>(
        Tok16, W16a, NTOK, DPROJ_N, DM_N, nullptr, nullptr, nullptr, ZX16);
    k_convprep<<<dim3(NTOK, 9), 256, 0, stream>>>(ZX16, cw, cb, dtb, al, XBC16, DTb, DLAb);
    k_scan<<<256, 256, 0, stream>>>(XBC16, DTb, DLAb, dd, YR);
    k_gatenorm<<<NTOK, 256, 0, stream>>>(YR, ZX16, nw, YN16);
    // out_proj: Tok16 = bn(YN16 x Wo^T) + Tok16   (64x64 -> 512 blocks)
    k_mgemm<1, 64, 64><<<dim3(16, 32), 256, 0, stream>>>(
        YN16, W16b, NTOK, DM_N, DI_N, nullptr, bbn, Tok16, Tok16);
    // ff1: H116 = relu(bn(Tok16 x w1^T + b1))   (64x128 -> 512 blocks)
    k_mgemm<2, 64, 128><<<dim3(16, 32), 256, 0, stream>>>(
        Tok16, W16c, NTOK, FFH_N, DM_N, b1, fbn1, nullptr, H116);
    // ff2: Tok16 = bn(H116 x w2^T + b2) + Tok16   (64x64 -> 512 blocks)
    k_mgemm<3, 64, 64><<<dim3(16, 32), 256, 0, stream>>>(
        H116, W16d, NTOK, DM_N, FFH_N, b2, fbn2, Tok16, Tok16);
  }
  k_transpose<<<dim3(32, 64), 256, 0, stream>>>(Tok16, (float*)d_out);
}